// Round 1
// baseline (480.759 us; speedup 1.0000x reference)
//
#include <hip/hip_runtime.h>
#include <hip/hip_bf16.h>
#include <stdint.h>

#define E_ 8
#define H_ 2048
#define I_ 1408
#define T_ 2048
#define K_ 2
#define G_ 128

typedef __bf16 bf16;
typedef bf16 bf16x8 __attribute__((ext_vector_type(8)));
typedef float f32x4 __attribute__((ext_vector_type(4)));

// fp4 e2m1 -> f32 (branchless select chain; no LUT memory traffic)
__device__ __forceinline__ float fp4_to_f32(uint32_t n) {
    uint32_t s = (n & 8u) << 28;
    uint32_t em = n & 7u;
    uint32_t bits = (em == 0u) ? 0u
                  : (em == 1u) ? 0x3f000000u
                  : (((126u + (em >> 1)) << 23) | ((em & 1u) << 22));
    return __uint_as_float(bits | s);
}

// ---------------- routing ----------------
__global__ void route_count(const int* __restrict__ topk_idx, int* __restrict__ counts) {
    int p = blockIdx.x * blockDim.x + threadIdx.x;
    if (p < T_ * K_) atomicAdd(&counts[topk_idx[p]], 1);
}

__global__ void route_scan(const int* __restrict__ counts, int* __restrict__ offsets) {
    if (threadIdx.x == 0) {
        int acc = 0;
        for (int e = 0; e < E_; e++) { offsets[e] = acc; acc += counts[e]; }
        offsets[E_] = acc;
    }
}

__global__ void route_fill(const int* __restrict__ topk_idx, const float* __restrict__ topk_w,
                           int* __restrict__ cursors, const int* __restrict__ offsets,
                           int* __restrict__ tok, float* __restrict__ wgt) {
    int p = blockIdx.x * blockDim.x + threadIdx.x;
    if (p < T_ * K_) {
        int e = topk_idx[p];
        int slot = atomicAdd(&cursors[e], 1);
        int idx = offsets[e] + slot;
        tok[idx] = p / K_;
        wgt[idx] = topk_w[p];
    }
}

// ---------------- GEMM1: h = silu(x@Wg^T) * (x@Wu^T), per expert ----------------
// tile: 64 tokens x 64 i-cols, K-step 32 over H. 4 waves in 2x2 grid, each wave 32x32.
__global__ __launch_bounds__(256)
void gemm1_kernel(const float* __restrict__ x,
                  const uint32_t* __restrict__ gate_packed,
                  const float* __restrict__ gate_scales,
                  const uint32_t* __restrict__ up_packed,
                  const float* __restrict__ up_scales,
                  const int* __restrict__ offsets,
                  const int* __restrict__ tok,
                  bf16* __restrict__ h_buf)
{
    const int e = blockIdx.z;
    const int row0 = offsets[e];
    const int cnt = offsets[e + 1] - row0;
    const int ty = blockIdx.y;
    if (ty * 64 >= cnt) return;
    const int itile = blockIdx.x;

    __shared__ __align__(16) bf16 xs[64][40];
    __shared__ __align__(16) bf16 wg[64][40];
    __shared__ __align__(16) bf16 wu[64][40];
    __shared__ int toks[64];

    const int tid = threadIdx.x;
    if (tid < 64) {
        int r = ty * 64 + tid;
        toks[tid] = tok[row0 + ((r < cnt) ? r : 0)];
    }
    __syncthreads();

    const int wave = tid >> 6;
    const int lane = tid & 63;
    const int wy = wave >> 1, wx = wave & 1;
    const int lrow = lane & 15, kq = lane >> 4;

    // staging assignments
    const int srow = tid >> 2;          // 0..63
    const int scol = (tid & 3) * 8;     // 0,8,16,24 (elements within 32-wide k)
    const int wcol = tid & 3;           // u32 column
    const int xtok = toks[srow];

    const uint32_t* gp = gate_packed + (size_t)e * I_ * (H_ / 8);
    const uint32_t* up = up_packed + (size_t)e * I_ * (H_ / 8);
    const float* gs = gate_scales + (size_t)e * (H_ / G_) * I_;
    const float* us = up_scales + (size_t)e * (H_ / G_) * I_;
    const int irow = itile * 64 + srow;

    f32x4 accg[2][2] = {};
    f32x4 accu[2][2] = {};

    for (int k0 = 0; k0 < H_; k0 += 32) {
        const int hg = k0 >> 7;  // scale group (G=128)
        __syncthreads();
        // stage x: 64 rows x 32 cols bf16
        {
            const float4 v0 = *(const float4*)&x[(size_t)xtok * H_ + k0 + scol];
            const float4 v1 = *(const float4*)&x[(size_t)xtok * H_ + k0 + scol + 4];
            bf16* d = &xs[srow][scol];
            d[0] = (bf16)v0.x; d[1] = (bf16)v0.y; d[2] = (bf16)v0.z; d[3] = (bf16)v0.w;
            d[4] = (bf16)v1.x; d[5] = (bf16)v1.y; d[6] = (bf16)v1.z; d[7] = (bf16)v1.w;
        }
        // stage gate+up weights: 64 i-rows x 32 h, dequant*scale -> bf16
        {
            const uint32_t pg = gp[(size_t)irow * (H_ / 8) + (k0 >> 3) + wcol];
            const uint32_t pu = up[(size_t)irow * (H_ / 8) + (k0 >> 3) + wcol];
            const float sg = gs[(size_t)hg * I_ + irow];
            const float su = us[(size_t)hg * I_ + irow];
            bf16* dg = &wg[srow][wcol * 8];
            bf16* du = &wu[srow][wcol * 8];
#pragma unroll
            for (int j = 0; j < 8; j++) {
                dg[j] = (bf16)(fp4_to_f32((pg >> (4 * j)) & 15u) * sg);
                du[j] = (bf16)(fp4_to_f32((pu >> (4 * j)) & 15u) * su);
            }
        }
        __syncthreads();

        bf16x8 a0 = *(const bf16x8*)&xs[wy * 32 + lrow][kq * 8];
        bf16x8 a1 = *(const bf16x8*)&xs[wy * 32 + 16 + lrow][kq * 8];
        bf16x8 bg0 = *(const bf16x8*)&wg[wx * 32 + lrow][kq * 8];
        bf16x8 bg1 = *(const bf16x8*)&wg[wx * 32 + 16 + lrow][kq * 8];
        bf16x8 bu0 = *(const bf16x8*)&wu[wx * 32 + lrow][kq * 8];
        bf16x8 bu1 = *(const bf16x8*)&wu[wx * 32 + 16 + lrow][kq * 8];

        accg[0][0] = __builtin_amdgcn_mfma_f32_16x16x32_bf16(a0, bg0, accg[0][0], 0, 0, 0);
        accg[0][1] = __builtin_amdgcn_mfma_f32_16x16x32_bf16(a0, bg1, accg[0][1], 0, 0, 0);
        accg[1][0] = __builtin_amdgcn_mfma_f32_16x16x32_bf16(a1, bg0, accg[1][0], 0, 0, 0);
        accg[1][1] = __builtin_amdgcn_mfma_f32_16x16x32_bf16(a1, bg1, accg[1][1], 0, 0, 0);
        accu[0][0] = __builtin_amdgcn_mfma_f32_16x16x32_bf16(a0, bu0, accu[0][0], 0, 0, 0);
        accu[0][1] = __builtin_amdgcn_mfma_f32_16x16x32_bf16(a0, bu1, accu[0][1], 0, 0, 0);
        accu[1][0] = __builtin_amdgcn_mfma_f32_16x16x32_bf16(a1, bu0, accu[1][0], 0, 0, 0);
        accu[1][1] = __builtin_amdgcn_mfma_f32_16x16x32_bf16(a1, bu1, accu[1][1], 0, 0, 0);
    }

    // epilogue: h = silu(g)*u -> bf16. C layout: col=lane&15, row=(lane>>4)*4+r
#pragma unroll
    for (int mi = 0; mi < 2; mi++) {
#pragma unroll
        for (int ni = 0; ni < 2; ni++) {
            const int icol = itile * 64 + wx * 32 + ni * 16 + lrow;
#pragma unroll
            for (int r = 0; r < 4; r++) {
                const int lr = wy * 32 + mi * 16 + kq * 4 + r;
                const int grow = ty * 64 + lr;
                if (grow < cnt) {
                    const float gv = accg[mi][ni][r];
                    const float hv = gv / (1.f + __expf(-gv)) * accu[mi][ni][r];
                    h_buf[(size_t)(row0 + grow) * I_ + icol] = (bf16)hv;
                }
            }
        }
    }
}

// ---------------- GEMM2: out[t] += w * (h @ Wd^T), per expert ----------------
__global__ __launch_bounds__(256)
void gemm2_kernel(const bf16* __restrict__ h_buf,
                  const uint32_t* __restrict__ down_packed,
                  const float* __restrict__ down_scales,
                  const int* __restrict__ offsets,
                  const int* __restrict__ tok,
                  const float* __restrict__ wgt,
                  float* __restrict__ out)
{
    const int e = blockIdx.z;
    const int row0 = offsets[e];
    const int cnt = offsets[e + 1] - row0;
    const int ty = blockIdx.y;
    if (ty * 64 >= cnt) return;
    const int htile = blockIdx.x;

    __shared__ __align__(16) bf16 hs[64][40];
    __shared__ __align__(16) bf16 wd[64][40];
    __shared__ int toks[64];
    __shared__ float wgts[64];

    const int tid = threadIdx.x;
    if (tid < 64) {
        int r = ty * 64 + tid;
        int src = row0 + ((r < cnt) ? r : 0);
        toks[tid] = tok[src];
        wgts[tid] = (r < cnt) ? wgt[src] : 0.f;
    }
    __syncthreads();

    const int wave = tid >> 6;
    const int lane = tid & 63;
    const int wy = wave >> 1, wx = wave & 1;
    const int lrow = lane & 15, kq = lane >> 4;

    const int srow = tid >> 2;
    const int scol = (tid & 3) * 8;
    const int wcol = tid & 3;
    const int hpair = row0 + min(ty * 64 + srow, cnt - 1);

    const uint32_t* dp = down_packed + (size_t)e * H_ * (I_ / 8);
    const float* ds = down_scales + (size_t)e * (I_ / G_) * H_;
    const int hcolw = htile * 64 + srow;

    f32x4 acc[2][2] = {};

    for (int k0 = 0; k0 < I_; k0 += 32) {
        const int ig = k0 >> 7;
        __syncthreads();
        // stage h tile (already bf16): 16B per thread
        {
            *(uint4*)&hs[srow][scol] = *(const uint4*)&h_buf[(size_t)hpair * I_ + k0 + scol];
        }
        // stage down weights
        {
            const uint32_t pd = dp[(size_t)hcolw * (I_ / 8) + (k0 >> 3) + wcol];
            const float sd = ds[(size_t)ig * H_ + hcolw];
            bf16* dd = &wd[srow][wcol * 8];
#pragma unroll
            for (int j = 0; j < 8; j++)
                dd[j] = (bf16)(fp4_to_f32((pd >> (4 * j)) & 15u) * sd);
        }
        __syncthreads();

        bf16x8 a0 = *(const bf16x8*)&hs[wy * 32 + lrow][kq * 8];
        bf16x8 a1 = *(const bf16x8*)&hs[wy * 32 + 16 + lrow][kq * 8];
        bf16x8 b0 = *(const bf16x8*)&wd[wx * 32 + lrow][kq * 8];
        bf16x8 b1 = *(const bf16x8*)&wd[wx * 32 + 16 + lrow][kq * 8];

        acc[0][0] = __builtin_amdgcn_mfma_f32_16x16x32_bf16(a0, b0, acc[0][0], 0, 0, 0);
        acc[0][1] = __builtin_amdgcn_mfma_f32_16x16x32_bf16(a0, b1, acc[0][1], 0, 0, 0);
        acc[1][0] = __builtin_amdgcn_mfma_f32_16x16x32_bf16(a1, b0, acc[1][0], 0, 0, 0);
        acc[1][1] = __builtin_amdgcn_mfma_f32_16x16x32_bf16(a1, b1, acc[1][1], 0, 0, 0);
    }

#pragma unroll
    for (int mi = 0; mi < 2; mi++) {
#pragma unroll
        for (int ni = 0; ni < 2; ni++) {
            const int col = htile * 64 + wx * 32 + ni * 16 + lrow;
#pragma unroll
            for (int r = 0; r < 4; r++) {
                const int lr = wy * 32 + mi * 16 + kq * 4 + r;
                if (ty * 64 + lr < cnt) {
                    atomicAdd(&out[(size_t)toks[lr] * H_ + col], acc[mi][ni][r] * wgts[lr]);
                }
            }
        }
    }
}

extern "C" void kernel_launch(void* const* d_in, const int* in_sizes, int n_in,
                              void* d_out, int out_size, void* d_ws, size_t ws_size,
                              hipStream_t stream) {
    const float* x = (const float*)d_in[0];
    const uint32_t* gate_packed = (const uint32_t*)d_in[1];
    const float* gate_scales = (const float*)d_in[2];
    const uint32_t* up_packed = (const uint32_t*)d_in[3];
    const float* up_scales = (const float*)d_in[4];
    const uint32_t* down_packed = (const uint32_t*)d_in[5];
    const float* down_scales = (const float*)d_in[6];
    const int* topk_idx = (const int*)d_in[7];
    const float* topk_w = (const float*)d_in[8];
    float* out = (float*)d_out;

    // workspace layout
    int* counts = (int*)d_ws;                 // 8
    int* cursors = counts + 8;                // 8
    int* offsets = counts + 16;               // 9 (16 slots reserved)
    int* tok = counts + 32;                   // 4096
    float* wgt = (float*)(counts + 32 + 4096);// 4096
    bf16* h_buf = (bf16*)(counts + 32 + 8192);// 4096 * 1408 bf16 (11.5 MB)

    hipMemsetAsync(d_out, 0, (size_t)out_size * sizeof(float), stream);
    hipMemsetAsync(d_ws, 0, 512, stream);

    route_count<<<(T_ * K_ + 255) / 256, 256, 0, stream>>>(topk_idx, counts);
    route_scan<<<1, 64, 0, stream>>>(counts, offsets);
    route_fill<<<(T_ * K_ + 255) / 256, 256, 0, stream>>>(topk_idx, topk_w, cursors, offsets, tok, wgt);

    dim3 g1(I_ / 64, (T_ * K_ + 63) / 64, E_);
    gemm1_kernel<<<g1, 256, 0, stream>>>(x, gate_packed, gate_scales, up_packed, up_scales,
                                         offsets, tok, h_buf);
    dim3 g2(H_ / 64, (T_ * K_ + 63) / 64, E_);
    gemm2_kernel<<<g2, 256, 0, stream>>>(h_buf, down_packed, down_scales,
                                         offsets, tok, wgt, out);
}

// Round 2
// 356.127 us; speedup vs baseline: 1.3500x; 1.3500x over previous
//
#include <hip/hip_runtime.h>
#include <hip/hip_bf16.h>
#include <stdint.h>

#define E_ 8
#define H_ 2048
#define I_ 1408
#define T_ 2048
#define K_ 2
#define G_ 128

typedef __bf16 bf16;
typedef bf16 bf16x8 __attribute__((ext_vector_type(8)));
typedef float f32x4 __attribute__((ext_vector_type(4)));

// fp4 e2m1 -> f32 (branchless)
__device__ __forceinline__ float fp4_to_f32(uint32_t n) {
    uint32_t s = (n & 8u) << 28;
    uint32_t em = n & 7u;
    uint32_t bits = (em == 0u) ? 0u
                  : (em == 1u) ? 0x3f000000u
                  : (((126u + (em >> 1)) << 23) | ((em & 1u) << 22));
    return __uint_as_float(bits | s);
}

// async 16B global -> LDS (direct-to-LDS DMA). LDS dest must be
// wave-uniform-base + lane*16, which all call sites below satisfy.
__device__ __forceinline__ void gld16(void* lds, const void* g) {
    __builtin_amdgcn_global_load_lds(
        (__attribute__((address_space(1))) void*)g,
        (__attribute__((address_space(3))) void*)lds, 16, 0, 0);
}

// ---------------- routing ----------------
__global__ void route_count(const int* __restrict__ topk_idx, int* __restrict__ counts) {
    int p = blockIdx.x * blockDim.x + threadIdx.x;
    if (p < T_ * K_) atomicAdd(&counts[topk_idx[p]], 1);
}

__global__ void route_scan(const int* __restrict__ counts, int* __restrict__ offsets) {
    if (threadIdx.x == 0) {
        int acc = 0;
        for (int e = 0; e < E_; e++) { offsets[e] = acc; acc += counts[e]; }
        offsets[E_] = acc;
    }
}

__global__ void route_fill(const int* __restrict__ topk_idx, const float* __restrict__ topk_w,
                           int* __restrict__ cursors, const int* __restrict__ offsets,
                           int* __restrict__ tok, float* __restrict__ wgt) {
    int p = blockIdx.x * blockDim.x + threadIdx.x;
    if (p < T_ * K_) {
        int e = topk_idx[p];
        int slot = atomicAdd(&cursors[e], 1);
        int idx = offsets[e] + slot;
        tok[idx] = p / K_;
        wgt[idx] = topk_w[p];
    }
}

// ---------------- pre-dequant: fp4 packed -> bf16 (scale folded) ----------------
// weight matrix: NROWS rows x (COLS_P*8) k-cols; scales [E][COLS_P/16][NROWS]
template<int COLS_P, int NROWS>
__global__ __launch_bounds__(256)
void dequant_kernel(const uint32_t* __restrict__ packed,
                    const float* __restrict__ scales,
                    uint4* __restrict__ outp) {
    const int e = blockIdx.y;
    const int flat = blockIdx.x * 256 + threadIdx.x;
    if (flat >= COLS_P * NROWS) return;
    const int row = flat / COLS_P;
    const int cp  = flat - row * COLS_P;
    const uint32_t p = packed[(size_t)e * COLS_P * NROWS + flat];
    const float s = scales[((size_t)e * (COLS_P / 16) + (cp >> 4)) * NROWS + row];
    union { uint4 u; bf16 h[8]; } r;
#pragma unroll
    for (int j = 0; j < 8; j++)
        r.h[j] = (bf16)(fp4_to_f32((p >> (4 * j)) & 15u) * s);
    outp[(size_t)e * COLS_P * NROWS + flat] = r.u;
}

// x f32 -> bf16
__global__ __launch_bounds__(256)
void xcast_kernel(const float* __restrict__ x, uint4* __restrict__ xb) {
    const int i = blockIdx.x * 256 + threadIdx.x;  // per 8 elements
    const float4 a = ((const float4*)x)[i * 2];
    const float4 b = ((const float4*)x)[i * 2 + 1];
    union { uint4 u; bf16 h[8]; } r;
    r.h[0] = (bf16)a.x; r.h[1] = (bf16)a.y; r.h[2] = (bf16)a.z; r.h[3] = (bf16)a.w;
    r.h[4] = (bf16)b.x; r.h[5] = (bf16)b.y; r.h[6] = (bf16)b.z; r.h[7] = (bf16)b.w;
    xb[i] = r.u;
}

// ---------------- GEMM1 (bf16 weights): h = silu(x@Wg^T)*(x@Wu^T) ----------------
// tile: 128 tokens x 64 i, BK=32. 4 waves 2x2; wave = 64m x 32n for BOTH g,u.
__global__ __launch_bounds__(256)
void gemm1b_kernel(const bf16* __restrict__ xb, const bf16* __restrict__ gw,
                   const bf16* __restrict__ uw, const int* __restrict__ offsets,
                   const int* __restrict__ tok, bf16* __restrict__ h_buf)
{
    const int e = blockIdx.z;
    const int row0 = offsets[e];
    const int cnt = offsets[e + 1] - row0;
    const int ty = blockIdx.y;
    if (ty * 128 >= cnt) return;
    const int itile = blockIdx.x;

    __shared__ __align__(16) bf16 xs[128][32];   // unpadded: global_load_lds + b128 reads
    __shared__ __align__(16) bf16 wgs[64][32];
    __shared__ __align__(16) bf16 wus[64][32];
    __shared__ int toks[128];

    const int tid = threadIdx.x;
    if (tid < 128) {
        int r = ty * 128 + tid;
        toks[tid] = tok[row0 + ((r < cnt) ? r : (cnt - 1))];
    }
    __syncthreads();

    const int srow = tid >> 2;          // 0..63
    const int scol = (tid & 3) * 8;     // element offset (16B chunks)
    const size_t t0 = toks[srow], t1 = toks[64 + srow];
    const bf16* xg0 = xb + t0 * H_ + scol;
    const bf16* xg1 = xb + t1 * H_ + scol;
    const bf16* gg = gw + ((size_t)e * I_ + itile * 64 + srow) * H_ + scol;
    const bf16* ug = uw + ((size_t)e * I_ + itile * 64 + srow) * H_ + scol;
    bf16* lx0 = &xs[srow][scol];        // flat = tid*16B  (lane-linear)
    bf16* lx1 = &xs[64 + srow][scol];
    bf16* lg  = &wgs[srow][scol];
    bf16* lu  = &wus[srow][scol];

    const int wave = tid >> 6, lane = tid & 63;
    const int wy = wave >> 1, wx = wave & 1;
    const int lrow = lane & 15, kq = lane >> 4;

    f32x4 accg[4][2] = {};
    f32x4 accu[4][2] = {};

    for (int k0 = 0; k0 < H_; k0 += 32) {
        gld16(lx0, xg0 + k0);
        gld16(lx1, xg1 + k0);
        gld16(lg,  gg + k0);
        gld16(lu,  ug + k0);
        __syncthreads();   // drains vmcnt -> LDS tiles ready

        bf16x8 a[4], bg[2], bu[2];
#pragma unroll
        for (int mi = 0; mi < 4; mi++)
            a[mi] = *(const bf16x8*)&xs[wy * 64 + mi * 16 + lrow][kq * 8];
#pragma unroll
        for (int ni = 0; ni < 2; ni++) {
            bg[ni] = *(const bf16x8*)&wgs[wx * 32 + ni * 16 + lrow][kq * 8];
            bu[ni] = *(const bf16x8*)&wus[wx * 32 + ni * 16 + lrow][kq * 8];
        }
#pragma unroll
        for (int mi = 0; mi < 4; mi++)
#pragma unroll
            for (int ni = 0; ni < 2; ni++) {
                accg[mi][ni] = __builtin_amdgcn_mfma_f32_16x16x32_bf16(a[mi], bg[ni], accg[mi][ni], 0, 0, 0);
                accu[mi][ni] = __builtin_amdgcn_mfma_f32_16x16x32_bf16(a[mi], bu[ni], accu[mi][ni], 0, 0, 0);
            }
        __syncthreads();   // all waves done reading before next stage overwrites
    }

    // C layout: col=lane&15, row=(lane>>4)*4+r
#pragma unroll
    for (int mi = 0; mi < 4; mi++)
#pragma unroll
        for (int ni = 0; ni < 2; ni++) {
            const int icol = itile * 64 + wx * 32 + ni * 16 + lrow;
#pragma unroll
            for (int r = 0; r < 4; r++) {
                const int grow = ty * 128 + wy * 64 + mi * 16 + kq * 4 + r;
                if (grow < cnt) {
                    const float gv = accg[mi][ni][r];
                    const float hv = gv / (1.f + __expf(-gv)) * accu[mi][ni][r];
                    h_buf[(size_t)(row0 + grow) * I_ + icol] = (bf16)hv;
                }
            }
        }
}

// ---------------- GEMM2 (bf16 weights): out[t] += w * (h @ Wd^T) ----------------
// tile: 128 tokens x 128 h-cols, BK=32. 4 waves 2x2; wave = 64x64 (4x4 accs).
__global__ __launch_bounds__(256)
void gemm2b_kernel(const bf16* __restrict__ h_buf, const bf16* __restrict__ dw,
                   const int* __restrict__ offsets, const int* __restrict__ tok,
                   const float* __restrict__ wgt, float* __restrict__ out)
{
    const int e = blockIdx.z;
    const int row0 = offsets[e];
    const int cnt = offsets[e + 1] - row0;
    const int ty = blockIdx.y;
    if (ty * 128 >= cnt) return;
    const int htile = blockIdx.x;

    __shared__ __align__(16) bf16 hs[128][32];
    __shared__ __align__(16) bf16 wds[128][32];
    __shared__ int toks[128];
    __shared__ float wgts[128];

    const int tid = threadIdx.x;
    if (tid < 128) {
        int r = ty * 128 + tid;
        int src = row0 + ((r < cnt) ? r : (cnt - 1));
        toks[tid] = tok[src];
        wgts[tid] = (r < cnt) ? wgt[src] : 0.f;
    }

    const int srow = tid >> 2;
    const int scol = (tid & 3) * 8;
    const int m0 = ty * 128 + srow;
    const int hr0 = row0 + ((m0 < cnt) ? m0 : (cnt - 1));
    const int m1 = m0 + 64;
    const int hr1 = row0 + ((m1 < cnt) ? m1 : (cnt - 1));
    const bf16* hg0 = h_buf + (size_t)hr0 * I_ + scol;
    const bf16* hg1 = h_buf + (size_t)hr1 * I_ + scol;
    const bf16* dg0 = dw + ((size_t)e * H_ + htile * 128 + srow) * I_ + scol;
    const bf16* dg1 = dw + ((size_t)e * H_ + htile * 128 + 64 + srow) * I_ + scol;
    bf16* lh0 = &hs[srow][scol];
    bf16* lh1 = &hs[64 + srow][scol];
    bf16* ld0 = &wds[srow][scol];
    bf16* ld1 = &wds[64 + srow][scol];

    const int wave = tid >> 6, lane = tid & 63;
    const int wy = wave >> 1, wx = wave & 1;
    const int lrow = lane & 15, kq = lane >> 4;

    f32x4 acc[4][4] = {};

    for (int k0 = 0; k0 < I_; k0 += 32) {
        gld16(lh0, hg0 + k0);
        gld16(lh1, hg1 + k0);
        gld16(ld0, dg0 + k0);
        gld16(ld1, dg1 + k0);
        __syncthreads();

        bf16x8 a[4], b[4];
#pragma unroll
        for (int mi = 0; mi < 4; mi++)
            a[mi] = *(const bf16x8*)&hs[wy * 64 + mi * 16 + lrow][kq * 8];
#pragma unroll
        for (int ni = 0; ni < 4; ni++)
            b[ni] = *(const bf16x8*)&wds[wx * 64 + ni * 16 + lrow][kq * 8];
#pragma unroll
        for (int mi = 0; mi < 4; mi++)
#pragma unroll
            for (int ni = 0; ni < 4; ni++)
                acc[mi][ni] = __builtin_amdgcn_mfma_f32_16x16x32_bf16(a[mi], b[ni], acc[mi][ni], 0, 0, 0);
        __syncthreads();
    }

#pragma unroll
    for (int mi = 0; mi < 4; mi++)
#pragma unroll
        for (int ni = 0; ni < 4; ni++) {
            const int col = htile * 128 + wx * 64 + ni * 16 + lrow;
#pragma unroll
            for (int r = 0; r < 4; r++) {
                const int lr = wy * 64 + mi * 16 + kq * 4 + r;
                if (ty * 128 + lr < cnt)
                    atomicAdd(&out[(size_t)toks[lr] * H_ + col], acc[mi][ni][r] * wgts[lr]);
            }
        }
}

// ================= FALLBACK (round-1 fused kernels, used if ws too small) =================
__global__ __launch_bounds__(256)
void gemm1_kernel(const float* __restrict__ x,
                  const uint32_t* __restrict__ gate_packed,
                  const float* __restrict__ gate_scales,
                  const uint32_t* __restrict__ up_packed,
                  const float* __restrict__ up_scales,
                  const int* __restrict__ offsets,
                  const int* __restrict__ tok,
                  bf16* __restrict__ h_buf)
{
    const int e = blockIdx.z;
    const int row0 = offsets[e];
    const int cnt = offsets[e + 1] - row0;
    const int ty = blockIdx.y;
    if (ty * 64 >= cnt) return;
    const int itile = blockIdx.x;

    __shared__ __align__(16) bf16 xs[64][40];
    __shared__ __align__(16) bf16 wg[64][40];
    __shared__ __align__(16) bf16 wu[64][40];
    __shared__ int toks[64];

    const int tid = threadIdx.x;
    if (tid < 64) {
        int r = ty * 64 + tid;
        toks[tid] = tok[row0 + ((r < cnt) ? r : 0)];
    }
    __syncthreads();

    const int wave = tid >> 6;
    const int lane = tid & 63;
    const int wy = wave >> 1, wx = wave & 1;
    const int lrow = lane & 15, kq = lane >> 4;

    const int srow = tid >> 2;
    const int scol = (tid & 3) * 8;
    const int wcol = tid & 3;
    const int xtok = toks[srow];

    const uint32_t* gp = gate_packed + (size_t)e * I_ * (H_ / 8);
    const uint32_t* up = up_packed + (size_t)e * I_ * (H_ / 8);
    const float* gs = gate_scales + (size_t)e * (H_ / G_) * I_;
    const float* us = up_scales + (size_t)e * (H_ / G_) * I_;
    const int irow = itile * 64 + srow;

    f32x4 accg[2][2] = {};
    f32x4 accu[2][2] = {};

    for (int k0 = 0; k0 < H_; k0 += 32) {
        const int hg = k0 >> 7;
        __syncthreads();
        {
            const float4 v0 = *(const float4*)&x[(size_t)xtok * H_ + k0 + scol];
            const float4 v1 = *(const float4*)&x[(size_t)xtok * H_ + k0 + scol + 4];
            bf16* d = &xs[srow][scol];
            d[0] = (bf16)v0.x; d[1] = (bf16)v0.y; d[2] = (bf16)v0.z; d[3] = (bf16)v0.w;
            d[4] = (bf16)v1.x; d[5] = (bf16)v1.y; d[6] = (bf16)v1.z; d[7] = (bf16)v1.w;
        }
        {
            const uint32_t pg = gp[(size_t)irow * (H_ / 8) + (k0 >> 3) + wcol];
            const uint32_t pu = up[(size_t)irow * (H_ / 8) + (k0 >> 3) + wcol];
            const float sg = gs[(size_t)hg * I_ + irow];
            const float su = us[(size_t)hg * I_ + irow];
            bf16* dg = &wg[srow][wcol * 8];
            bf16* du = &wu[srow][wcol * 8];
#pragma unroll
            for (int j = 0; j < 8; j++) {
                dg[j] = (bf16)(fp4_to_f32((pg >> (4 * j)) & 15u) * sg);
                du[j] = (bf16)(fp4_to_f32((pu >> (4 * j)) & 15u) * su);
            }
        }
        __syncthreads();

        bf16x8 a0 = *(const bf16x8*)&xs[wy * 32 + lrow][kq * 8];
        bf16x8 a1 = *(const bf16x8*)&xs[wy * 32 + 16 + lrow][kq * 8];
        bf16x8 bg0 = *(const bf16x8*)&wg[wx * 32 + lrow][kq * 8];
        bf16x8 bg1 = *(const bf16x8*)&wg[wx * 32 + 16 + lrow][kq * 8];
        bf16x8 bu0 = *(const bf16x8*)&wu[wx * 32 + lrow][kq * 8];
        bf16x8 bu1 = *(const bf16x8*)&wu[wx * 32 + 16 + lrow][kq * 8];

        accg[0][0] = __builtin_amdgcn_mfma_f32_16x16x32_bf16(a0, bg0, accg[0][0], 0, 0, 0);
        accg[0][1] = __builtin_amdgcn_mfma_f32_16x16x32_bf16(a0, bg1, accg[0][1], 0, 0, 0);
        accg[1][0] = __builtin_amdgcn_mfma_f32_16x16x32_bf16(a1, bg0, accg[1][0], 0, 0, 0);
        accg[1][1] = __builtin_amdgcn_mfma_f32_16x16x32_bf16(a1, bg1, accg[1][1], 0, 0, 0);
        accu[0][0] = __builtin_amdgcn_mfma_f32_16x16x32_bf16(a0, bu0, accu[0][0], 0, 0, 0);
        accu[0][1] = __builtin_amdgcn_mfma_f32_16x16x32_bf16(a0, bu1, accu[0][1], 0, 0, 0);
        accu[1][0] = __builtin_amdgcn_mfma_f32_16x16x32_bf16(a1, bu0, accu[1][0], 0, 0, 0);
        accu[1][1] = __builtin_amdgcn_mfma_f32_16x16x32_bf16(a1, bu1, accu[1][1], 0, 0, 0);
    }

#pragma unroll
    for (int mi = 0; mi < 2; mi++)
#pragma unroll
        for (int ni = 0; ni < 2; ni++) {
            const int icol = itile * 64 + wx * 32 + ni * 16 + lrow;
#pragma unroll
            for (int r = 0; r < 4; r++) {
                const int lr = wy * 32 + mi * 16 + kq * 4 + r;
                const int grow = ty * 64 + lr;
                if (grow < cnt) {
                    const float gv = accg[mi][ni][r];
                    const float hv = gv / (1.f + __expf(-gv)) * accu[mi][ni][r];
                    h_buf[(size_t)(row0 + grow) * I_ + icol] = (bf16)hv;
                }
            }
        }
}

__global__ __launch_bounds__(256)
void gemm2_kernel(const bf16* __restrict__ h_buf,
                  const uint32_t* __restrict__ down_packed,
                  const float* __restrict__ down_scales,
                  const int* __restrict__ offsets,
                  const int* __restrict__ tok,
                  const float* __restrict__ wgt,
                  float* __restrict__ out)
{
    const int e = blockIdx.z;
    const int row0 = offsets[e];
    const int cnt = offsets[e + 1] - row0;
    const int ty = blockIdx.y;
    if (ty * 64 >= cnt) return;
    const int htile = blockIdx.x;

    __shared__ __align__(16) bf16 hs[64][40];
    __shared__ __align__(16) bf16 wd[64][40];
    __shared__ int toks[64];
    __shared__ float wgts[64];

    const int tid = threadIdx.x;
    if (tid < 64) {
        int r = ty * 64 + tid;
        int src = row0 + ((r < cnt) ? r : 0);
        toks[tid] = tok[src];
        wgts[tid] = (r < cnt) ? wgt[src] : 0.f;
    }
    __syncthreads();

    const int wave = tid >> 6;
    const int lane = tid & 63;
    const int wy = wave >> 1, wx = wave & 1;
    const int lrow = lane & 15, kq = lane >> 4;

    const int srow = tid >> 2;
    const int scol = (tid & 3) * 8;
    const int wcol = tid & 3;
    const int hpair = row0 + min(ty * 64 + srow, cnt - 1);

    const uint32_t* dp = down_packed + (size_t)e * H_ * (I_ / 8);
    const float* ds = down_scales + (size_t)e * (I_ / G_) * H_;
    const int hcolw = htile * 64 + srow;

    f32x4 acc[2][2] = {};

    for (int k0 = 0; k0 < I_; k0 += 32) {
        const int ig = k0 >> 7;
        __syncthreads();
        {
            *(uint4*)&hs[srow][scol] = *(const uint4*)&h_buf[(size_t)hpair * I_ + k0 + scol];
        }
        {
            const uint32_t pd = dp[(size_t)hcolw * (I_ / 8) + (k0 >> 3) + wcol];
            const float sd = ds[(size_t)ig * H_ + hcolw];
            bf16* dd = &wd[srow][wcol * 8];
#pragma unroll
            for (int j = 0; j < 8; j++)
                dd[j] = (bf16)(fp4_to_f32((pd >> (4 * j)) & 15u) * sd);
        }
        __syncthreads();

        bf16x8 a0 = *(const bf16x8*)&hs[wy * 32 + lrow][kq * 8];
        bf16x8 a1 = *(const bf16x8*)&hs[wy * 32 + 16 + lrow][kq * 8];
        bf16x8 b0 = *(const bf16x8*)&wd[wx * 32 + lrow][kq * 8];
        bf16x8 b1 = *(const bf16x8*)&wd[wx * 32 + 16 + lrow][kq * 8];

        acc[0][0] = __builtin_amdgcn_mfma_f32_16x16x32_bf16(a0, b0, acc[0][0], 0, 0, 0);
        acc[0][1] = __builtin_amdgcn_mfma_f32_16x16x32_bf16(a0, b1, acc[0][1], 0, 0, 0);
        acc[1][0] = __builtin_amdgcn_mfma_f32_16x16x32_bf16(a1, b0, acc[1][0], 0, 0, 0);
        acc[1][1] = __builtin_amdgcn_mfma_f32_16x16x32_bf16(a1, b1, acc[1][1], 0, 0, 0);
    }

#pragma unroll
    for (int mi = 0; mi < 2; mi++)
#pragma unroll
        for (int ni = 0; ni < 2; ni++) {
            const int col = htile * 64 + wx * 32 + ni * 16 + lrow;
#pragma unroll
            for (int r = 0; r < 4; r++) {
                const int lr = wy * 32 + mi * 16 + kq * 4 + r;
                if (ty * 64 + lr < cnt) {
                    atomicAdd(&out[(size_t)toks[lr] * H_ + col], acc[mi][ni][r] * wgts[lr]);
                }
            }
        }
}

extern "C" void kernel_launch(void* const* d_in, const int* in_sizes, int n_in,
                              void* d_out, int out_size, void* d_ws, size_t ws_size,
                              hipStream_t stream) {
    const float* x = (const float*)d_in[0];
    const uint32_t* gate_packed = (const uint32_t*)d_in[1];
    const float* gate_scales = (const float*)d_in[2];
    const uint32_t* up_packed = (const uint32_t*)d_in[3];
    const float* up_scales = (const float*)d_in[4];
    const uint32_t* down_packed = (const uint32_t*)d_in[5];
    const float* down_scales = (const float*)d_in[6];
    const int* topk_idx = (const int*)d_in[7];
    const float* topk_w = (const float*)d_in[8];
    float* out = (float*)d_out;

    // workspace layout (bytes)
    char* ws = (char*)d_ws;
    int* counts  = (int*)ws;            // 32 B
    int* cursors = (int*)(ws + 32);     // 32 B
    int* offsets = (int*)(ws + 64);     // 64 B
    int* tok     = (int*)(ws + 128);    // 16384 B
    float* wgt   = (float*)(ws + 16512);// 16384 B
    bf16* h_buf  = (bf16*)(ws + 32896); // 11,534,336 B
    const size_t off_xb   = 32896ull + 11534336ull;          // 11,567,232
    const size_t off_gate = off_xb + 8388608ull;             // 19,955,840
    const size_t off_up   = off_gate + 46137344ull;          // 66,093,184
    const size_t off_down = off_up + 46137344ull;            // 112,230,528
    const size_t ws_needed = off_down + 46137344ull;         // 158,367,872
    bf16* xb      = (bf16*)(ws + off_xb);
    bf16* gate_bf = (bf16*)(ws + off_gate);
    bf16* up_bf   = (bf16*)(ws + off_up);
    bf16* down_bf = (bf16*)(ws + off_down);

    hipMemsetAsync(d_out, 0, (size_t)out_size * sizeof(float), stream);
    hipMemsetAsync(d_ws, 0, 512, stream);

    route_count<<<(T_ * K_ + 255) / 256, 256, 0, stream>>>(topk_idx, counts);
    route_scan<<<1, 64, 0, stream>>>(counts, offsets);
    route_fill<<<(T_ * K_ + 255) / 256, 256, 0, stream>>>(topk_idx, topk_w, cursors, offsets, tok, wgt);

    if (ws_size >= ws_needed) {
        // pre-dequant path
        xcast_kernel<<<T_ * H_ / 8 / 256, 256, 0, stream>>>(x, (uint4*)xb);
        dequant_kernel<H_ / 8, I_><<<dim3((H_ / 8) * I_ / 256, E_), 256, 0, stream>>>(
            gate_packed, gate_scales, (uint4*)gate_bf);
        dequant_kernel<H_ / 8, I_><<<dim3((H_ / 8) * I_ / 256, E_), 256, 0, stream>>>(
            up_packed, up_scales, (uint4*)up_bf);
        dequant_kernel<I_ / 8, H_><<<dim3((I_ / 8) * H_ / 256, E_), 256, 0, stream>>>(
            down_packed, down_scales, (uint4*)down_bf);

        dim3 g1(I_ / 64, 32, E_);
        gemm1b_kernel<<<g1, 256, 0, stream>>>(xb, gate_bf, up_bf, offsets, tok, h_buf);
        dim3 g2(H_ / 128, 32, E_);
        gemm2b_kernel<<<g2, 256, 0, stream>>>(h_buf, down_bf, offsets, tok, wgt, out);
    } else {
        // fallback: round-1 fused kernels
        dim3 g1(I_ / 64, (T_ * K_ + 63) / 64, E_);
        gemm1_kernel<<<g1, 256, 0, stream>>>(x, gate_packed, gate_scales, up_packed, up_scales,
                                             offsets, tok, h_buf);
        dim3 g2(H_ / 64, (T_ * K_ + 63) / 64, E_);
        gemm2_kernel<<<g2, 256, 0, stream>>>(h_buf, down_packed, down_scales,
                                             offsets, tok, wgt, out);
    }
}

// Round 4
// 345.105 us; speedup vs baseline: 1.3931x; 1.0319x over previous
//
#include <hip/hip_runtime.h>
#include <hip/hip_bf16.h>
#include <stdint.h>

#define E_ 8
#define H_ 2048
#define I_ 1408
#define T_ 2048
#define K_ 2
#define G_ 128

typedef __bf16 bf16;
typedef bf16 bf16x8 __attribute__((ext_vector_type(8)));
typedef float f32x4 __attribute__((ext_vector_type(4)));

__device__ __forceinline__ uint32_t prm(uint32_t hi, uint32_t lo, uint32_t sel) {
    return __builtin_amdgcn_perm(hi, lo, sel);  // sel byte 0-3 -> lo bytes, 4-7 -> hi bytes
}

// Scale-folded dequant tables: bf16(e2m1[m]*s) split into high/low byte LUTs.
struct DequantTab { uint32_t thi0, thi1, tlo0, tlo1; };

__device__ __forceinline__ DequantTab build_tab(float s) {
    union { bf16 h[8]; uint32_t u[4]; } tb;
    tb.h[0] = (bf16)(0.0f);
    tb.h[1] = (bf16)(0.5f * s);
    tb.h[2] = (bf16)(1.0f * s);
    tb.h[3] = (bf16)(1.5f * s);
    tb.h[4] = (bf16)(2.0f * s);
    tb.h[5] = (bf16)(3.0f * s);
    tb.h[6] = (bf16)(4.0f * s);
    tb.h[7] = (bf16)(6.0f * s);
    DequantTab t;
    t.thi0 = prm(tb.u[1], tb.u[0], 0x07050301u);  // high bytes of m=0..3
    t.tlo0 = prm(tb.u[1], tb.u[0], 0x06040200u);  // low  bytes of m=0..3
    t.thi1 = prm(tb.u[3], tb.u[2], 0x07050301u);  // high bytes of m=4..7
    t.tlo1 = prm(tb.u[3], tb.u[2], 0x06040200u);
    return t;
}

// 8 fp4 (one u32, k-order) -> 8 scaled bf16 as uint4. 21 VALU ops.
__device__ __forceinline__ uint4 dequant8t(uint32_t p, const DequantTab& t) {
    const uint32_t pr = p >> 4;
    const uint32_t pe = p  & 0x07070707u;   // magnitudes of nibbles 0,2,4,6
    const uint32_t po = pr & 0x07070707u;   // magnitudes of nibbles 1,3,5,7
    const uint32_t He = prm(t.thi1, t.thi0, pe) | ((p  & 0x08080808u) << 4);
    const uint32_t Le = prm(t.tlo1, t.tlo0, pe);
    const uint32_t Ho = prm(t.thi1, t.thi0, po) | ((pr & 0x08080808u) << 4);
    const uint32_t Lo = prm(t.tlo1, t.tlo0, po);
    const uint32_t E01 = prm(He, Le, 0x05010400u);  // bf16(n0), bf16(n2)
    const uint32_t E23 = prm(He, Le, 0x07030602u);  // bf16(n4), bf16(n6)
    const uint32_t O01 = prm(Ho, Lo, 0x05010400u);  // bf16(n1), bf16(n3)
    const uint32_t O23 = prm(Ho, Lo, 0x07030602u);  // bf16(n5), bf16(n7)
    return make_uint4(prm(O01, E01, 0x05040100u),   // n0,n1
                      prm(O01, E01, 0x07060302u),   // n2,n3
                      prm(O23, E23, 0x05040100u),   // n4,n5
                      prm(O23, E23, 0x07060302u));  // n6,n7
}

// async 16B global -> LDS DMA (wave-uniform-base + lane-linear dest)
__device__ __forceinline__ void gld16(void* lds, const void* g) {
    __builtin_amdgcn_global_load_lds(
        (__attribute__((address_space(1))) void*)g,
        (__attribute__((address_space(3))) void*)lds, 16, 0, 0);
}

// ---------------- routing ----------------
__global__ void route_count(const int* __restrict__ topk_idx, int* __restrict__ counts) {
    int p = blockIdx.x * blockDim.x + threadIdx.x;
    if (p < T_ * K_) atomicAdd(&counts[topk_idx[p]], 1);
}

__global__ void route_scan(const int* __restrict__ counts, int* __restrict__ offsets) {
    if (threadIdx.x == 0) {
        int acc = 0;
        for (int e = 0; e < E_; e++) { offsets[e] = acc; acc += counts[e]; }
        offsets[E_] = acc;
    }
}

__global__ void route_fill(const int* __restrict__ topk_idx, const float* __restrict__ topk_w,
                           int* __restrict__ cursors, const int* __restrict__ offsets,
                           int* __restrict__ tok, float* __restrict__ wgt) {
    int p = blockIdx.x * blockDim.x + threadIdx.x;
    if (p < T_ * K_) {
        int e = topk_idx[p];
        int slot = atomicAdd(&cursors[e], 1);
        int idx = offsets[e] + slot;
        tok[idx] = p / K_;
        wgt[idx] = topk_w[p];
    }
}

// x f32 -> bf16
__global__ __launch_bounds__(256)
void xcast_kernel(const float* __restrict__ x, uint4* __restrict__ xb) {
    const int i = blockIdx.x * 256 + threadIdx.x;  // per 8 elements
    const float4 a = ((const float4*)x)[i * 2];
    const float4 b = ((const float4*)x)[i * 2 + 1];
    union { uint4 u; bf16 h[8]; } r;
    r.h[0] = (bf16)a.x; r.h[1] = (bf16)a.y; r.h[2] = (bf16)a.z; r.h[3] = (bf16)a.w;
    r.h[4] = (bf16)b.x; r.h[5] = (bf16)b.y; r.h[6] = (bf16)b.z; r.h[7] = (bf16)b.w;
    xb[i] = r.u;
}

// ---------------- GEMM1 (fused LUT dequant): h = silu(x@Wg^T)*(x@Wu^T) ----------------
// tile: 128 tokens x 64 i, BK=32, scale-group loop of 128 (=4 steps).
// 4 waves 2x2; wave = 64m x 32n for BOTH g,u => 16 MFMA/wave/step.
__global__ __launch_bounds__(256)
void gemm1f_kernel(const bf16* __restrict__ xb,
                   const uint32_t* __restrict__ gate_packed,
                   const float* __restrict__ gate_scales,
                   const uint32_t* __restrict__ up_packed,
                   const float* __restrict__ up_scales,
                   const int* __restrict__ offsets,
                   const int* __restrict__ tok, bf16* __restrict__ h_buf)
{
    const int e = blockIdx.z;
    const int row0 = offsets[e];
    const int cnt = offsets[e + 1] - row0;
    const int ty = blockIdx.y;
    if (ty * 128 >= cnt) return;
    const int itile = blockIdx.x;

    __shared__ __align__(16) bf16 xs[128][32];
    __shared__ __align__(16) bf16 wgs[64][32];
    __shared__ __align__(16) bf16 wus[64][32];
    __shared__ int toks[128];

    const int tid = threadIdx.x;
    if (tid < 128) {
        int r = ty * 128 + tid;
        toks[tid] = tok[row0 + ((r < cnt) ? r : (cnt - 1))];
    }
    __syncthreads();

    // staging roles
    const int srow = tid >> 2;          // 0..63
    const int scol = (tid & 3) * 8;     // x-stage element offset (16B chunks)
    const int wcol = tid & 3;           // weight u32 col within 32-k step
    const size_t t0 = toks[srow], t1 = toks[64 + srow];
    const bf16* xg0 = xb + t0 * H_ + scol;
    const bf16* xg1 = xb + t1 * H_ + scol;
    bf16* lx0 = &xs[srow][scol];
    bf16* lx1 = &xs[64 + srow][scol];

    const int irow = itile * 64 + srow;
    const uint32_t* gp_row = gate_packed + (size_t)e * I_ * (H_ / 8) + (size_t)irow * (H_ / 8) + wcol;
    const uint32_t* up_row = up_packed + (size_t)e * I_ * (H_ / 8) + (size_t)irow * (H_ / 8) + wcol;
    const float* gs_row = gate_scales + (size_t)e * (H_ / G_) * I_ + irow;
    const float* us_row = up_scales + (size_t)e * (H_ / G_) * I_ + irow;
    uint4* lwg = (uint4*)&wgs[srow][wcol * 8];
    uint4* lwu = (uint4*)&wus[srow][wcol * 8];

    const int wave = tid >> 6, lane = tid & 63;
    const int wy = wave >> 1, wx = wave & 1;
    const int lrow = lane & 15, kq = lane >> 4;

    f32x4 accg[4][2] = {};
    f32x4 accu[4][2] = {};

    for (int kg = 0; kg < H_ / G_; kg++) {   // scale group = 128 k = 4 steps
        const DequantTab tg = build_tab(gs_row[kg * I_]);
        const DequantTab tu = build_tab(us_row[kg * I_]);
#pragma unroll
        for (int kk = 0; kk < 4; kk++) {
            const int k0 = kg * 128 + kk * 32;
            gld16(lx0, xg0 + k0);
            gld16(lx1, xg1 + k0);
            const uint32_t pg = gp_row[kg * 16 + kk * 4];
            const uint32_t pu = up_row[kg * 16 + kk * 4];
            *lwg = dequant8t(pg, tg);
            *lwu = dequant8t(pu, tu);
            __syncthreads();

            bf16x8 a[4], bg[2], bu[2];
#pragma unroll
            for (int mi = 0; mi < 4; mi++)
                a[mi] = *(const bf16x8*)&xs[wy * 64 + mi * 16 + lrow][kq * 8];
#pragma unroll
            for (int ni = 0; ni < 2; ni++) {
                bg[ni] = *(const bf16x8*)&wgs[wx * 32 + ni * 16 + lrow][kq * 8];
                bu[ni] = *(const bf16x8*)&wus[wx * 32 + ni * 16 + lrow][kq * 8];
            }
#pragma unroll
            for (int mi = 0; mi < 4; mi++)
#pragma unroll
                for (int ni = 0; ni < 2; ni++) {
                    accg[mi][ni] = __builtin_amdgcn_mfma_f32_16x16x32_bf16(a[mi], bg[ni], accg[mi][ni], 0, 0, 0);
                    accu[mi][ni] = __builtin_amdgcn_mfma_f32_16x16x32_bf16(a[mi], bu[ni], accu[mi][ni], 0, 0, 0);
                }
            __syncthreads();
        }
    }

    // C layout: col=lane&15, row=(lane>>4)*4+r
#pragma unroll
    for (int mi = 0; mi < 4; mi++)
#pragma unroll
        for (int ni = 0; ni < 2; ni++) {
            const int icol = itile * 64 + wx * 32 + ni * 16 + lrow;
#pragma unroll
            for (int r = 0; r < 4; r++) {
                const int grow = ty * 128 + wy * 64 + mi * 16 + kq * 4 + r;
                if (grow < cnt) {
                    const float gv = accg[mi][ni][r];
                    const float hv = gv / (1.f + __expf(-gv)) * accu[mi][ni][r];
                    h_buf[(size_t)(row0 + grow) * I_ + icol] = (bf16)hv;
                }
            }
        }
}

// ---------------- GEMM2 (fused LUT dequant): out[t] += w * (h @ Wd^T) ----------------
// tile: 128 tokens x 128 h-cols, BK=32. 4 waves 2x2; wave = 64x64 (4x4 accs).
__global__ __launch_bounds__(256)
void gemm2f_kernel(const bf16* __restrict__ h_buf,
                   const uint32_t* __restrict__ down_packed,
                   const float* __restrict__ down_scales,
                   const int* __restrict__ offsets, const int* __restrict__ tok,
                   const float* __restrict__ wgt, float* __restrict__ out)
{
    const int e = blockIdx.z;
    const int row0 = offsets[e];
    const int cnt = offsets[e + 1] - row0;
    const int ty = blockIdx.y;
    if (ty * 128 >= cnt) return;
    const int htile = blockIdx.x;

    __shared__ __align__(16) bf16 hs[128][32];
    __shared__ __align__(16) bf16 wds[128][32];
    __shared__ int toks[128];
    __shared__ float wgts[128];

    const int tid = threadIdx.x;
    if (tid < 128) {
        int r = ty * 128 + tid;
        int src = row0 + ((r < cnt) ? r : (cnt - 1));
        toks[tid] = tok[src];
        wgts[tid] = (r < cnt) ? wgt[src] : 0.f;
    }
    __syncthreads();

    // h staging: srow covers rows {srow, 64+srow} via DMA
    const int srow = tid >> 2;
    const int scol = (tid & 3) * 8;
    const int m0 = ty * 128 + srow;
    const int hr0 = row0 + ((m0 < cnt) ? m0 : (cnt - 1));
    const int m1 = m0 + 64;
    const int hr1 = row0 + ((m1 < cnt) ? m1 : (cnt - 1));
    const bf16* hg0 = h_buf + (size_t)hr0 * I_ + scol;
    const bf16* hg1 = h_buf + (size_t)hr1 * I_ + scol;
    bf16* lh0 = &hs[srow][scol];
    bf16* lh1 = &hs[64 + srow][scol];

    // weight staging: thread covers 1 of 128 rows, 2 consecutive u32 (16 nibbles)
    const int srow2 = tid >> 1;          // 0..127
    const int wcol2 = (tid & 1) * 2;     // u32 col {0,2}
    const int hrow = htile * 128 + srow2;
    const uint32_t* dp_row = down_packed + (size_t)e * H_ * (I_ / 8) + (size_t)hrow * (I_ / 8) + wcol2;
    const float* ds_row = down_scales + (size_t)e * (I_ / G_) * H_ + hrow;
    uint4* lwd0 = (uint4*)&wds[srow2][wcol2 * 8];
    uint4* lwd1 = (uint4*)&wds[srow2][wcol2 * 8 + 8];

    const int wave = tid >> 6, lane = tid & 63;
    const int wy = wave >> 1, wx = wave & 1;
    const int lrow = lane & 15, kq = lane >> 4;

    f32x4 acc[4][4] = {};

    for (int kg = 0; kg < I_ / G_; kg++) {   // 11 scale groups
        const DequantTab td = build_tab(ds_row[kg * H_]);
#pragma unroll
        for (int kk = 0; kk < 4; kk++) {
            const int k0 = kg * 128 + kk * 32;
            gld16(lh0, hg0 + k0);
            gld16(lh1, hg1 + k0);
            const uint32_t pd0 = dp_row[kg * 16 + kk * 4];
            const uint32_t pd1 = dp_row[kg * 16 + kk * 4 + 1];
            *lwd0 = dequant8t(pd0, td);
            *lwd1 = dequant8t(pd1, td);
            __syncthreads();

            bf16x8 a[4], b[4];
#pragma unroll
            for (int mi = 0; mi < 4; mi++)
                a[mi] = *(const bf16x8*)&hs[wy * 64 + mi * 16 + lrow][kq * 8];
#pragma unroll
            for (int ni = 0; ni < 4; ni++)
                b[ni] = *(const bf16x8*)&wds[wx * 64 + ni * 16 + lrow][kq * 8];
#pragma unroll
            for (int mi = 0; mi < 4; mi++)
#pragma unroll
                for (int ni = 0; ni < 4; ni++)
                    acc[mi][ni] = __builtin_amdgcn_mfma_f32_16x16x32_bf16(a[mi], b[ni], acc[mi][ni], 0, 0, 0);
            __syncthreads();
        }
    }

#pragma unroll
    for (int mi = 0; mi < 4; mi++)
#pragma unroll
        for (int ni = 0; ni < 4; ni++) {
            const int col = htile * 128 + wx * 64 + ni * 16 + lrow;
#pragma unroll
            for (int r = 0; r < 4; r++) {
                const int lr = wy * 64 + mi * 16 + kq * 4 + r;
                if (ty * 128 + lr < cnt)
                    atomicAdd(&out[(size_t)toks[lr] * H_ + col], acc[mi][ni][r] * wgts[lr]);
            }
        }
}

extern "C" void kernel_launch(void* const* d_in, const int* in_sizes, int n_in,
                              void* d_out, int out_size, void* d_ws, size_t ws_size,
                              hipStream_t stream) {
    const float* x = (const float*)d_in[0];
    const uint32_t* gate_packed = (const uint32_t*)d_in[1];
    const float* gate_scales = (const float*)d_in[2];
    const uint32_t* up_packed = (const uint32_t*)d_in[3];
    const float* up_scales = (const float*)d_in[4];
    const uint32_t* down_packed = (const uint32_t*)d_in[5];
    const float* down_scales = (const float*)d_in[6];
    const int* topk_idx = (const int*)d_in[7];
    const float* topk_w = (const float*)d_in[8];
    float* out = (float*)d_out;

    // workspace layout (bytes)
    char* ws = (char*)d_ws;
    int* counts  = (int*)ws;            // 32 B
    int* cursors = (int*)(ws + 32);     // 32 B
    int* offsets = (int*)(ws + 64);     // 64 B
    int* tok     = (int*)(ws + 128);    // 16384 B
    float* wgt   = (float*)(ws + 16512);// 16384 B
    bf16* h_buf  = (bf16*)(ws + 32896); // 11,534,336 B
    bf16* xb     = (bf16*)(ws + 32896 + 11534336ull); // 8,388,608 B

    hipMemsetAsync(d_out, 0, (size_t)out_size * sizeof(float), stream);
    hipMemsetAsync(d_ws, 0, 512, stream);

    route_count<<<(T_ * K_ + 255) / 256, 256, 0, stream>>>(topk_idx, counts);
    route_scan<<<1, 64, 0, stream>>>(counts, offsets);
    route_fill<<<(T_ * K_ + 255) / 256, 256, 0, stream>>>(topk_idx, topk_w, cursors, offsets, tok, wgt);
    xcast_kernel<<<T_ * H_ / 8 / 256, 256, 0, stream>>>(x, (uint4*)xb);

    dim3 g1(I_ / 64, 32, E_);
    gemm1f_kernel<<<g1, 256, 0, stream>>>(xb, gate_packed, gate_scales, up_packed, up_scales,
                                          offsets, tok, h_buf);
    dim3 g2(H_ / 128, 32, E_);
    gemm2f_kernel<<<g2, 256, 0, stream>>>(h_buf, down_packed, down_scales,
                                          offsets, tok, wgt, out);
}

// Round 5
// 333.323 us; speedup vs baseline: 1.4423x; 1.0353x over previous
//
#include <hip/hip_runtime.h>
#include <hip/hip_bf16.h>
#include <stdint.h>

#define E_ 8
#define H_ 2048
#define I_ 1408
#define T_ 2048
#define K_ 2
#define G_ 128

typedef __bf16 bf16;
typedef bf16 bf16x8 __attribute__((ext_vector_type(8)));
typedef float f32x4 __attribute__((ext_vector_type(4)));

__device__ __forceinline__ uint32_t prm(uint32_t hi, uint32_t lo, uint32_t sel) {
    return __builtin_amdgcn_perm(hi, lo, sel);
}

// Scale-folded dequant tables: bf16(e2m1[m]*s) split into high/low byte LUTs.
struct DequantTab { uint32_t thi0, thi1, tlo0, tlo1; };

__device__ __forceinline__ DequantTab build_tab(float s) {
    union { bf16 h[8]; uint32_t u[4]; } tb;
    tb.h[0] = (bf16)(0.0f);
    tb.h[1] = (bf16)(0.5f * s);
    tb.h[2] = (bf16)(1.0f * s);
    tb.h[3] = (bf16)(1.5f * s);
    tb.h[4] = (bf16)(2.0f * s);
    tb.h[5] = (bf16)(3.0f * s);
    tb.h[6] = (bf16)(4.0f * s);
    tb.h[7] = (bf16)(6.0f * s);
    DequantTab t;
    t.thi0 = prm(tb.u[1], tb.u[0], 0x07050301u);
    t.tlo0 = prm(tb.u[1], tb.u[0], 0x06040200u);
    t.thi1 = prm(tb.u[3], tb.u[2], 0x07050301u);
    t.tlo1 = prm(tb.u[3], tb.u[2], 0x06040200u);
    return t;
}

// 8 fp4 (one u32, k-order) -> 8 scaled bf16 as uint4. ~21 VALU ops.
__device__ __forceinline__ uint4 dequant8t(uint32_t p, const DequantTab& t) {
    const uint32_t pr = p >> 4;
    const uint32_t pe = p  & 0x07070707u;
    const uint32_t po = pr & 0x07070707u;
    const uint32_t He = prm(t.thi1, t.thi0, pe) | ((p  & 0x08080808u) << 4);
    const uint32_t Le = prm(t.tlo1, t.tlo0, pe);
    const uint32_t Ho = prm(t.thi1, t.thi0, po) | ((pr & 0x08080808u) << 4);
    const uint32_t Lo = prm(t.tlo1, t.tlo0, po);
    const uint32_t E01 = prm(He, Le, 0x05010400u);
    const uint32_t E23 = prm(He, Le, 0x07030602u);
    const uint32_t O01 = prm(Ho, Lo, 0x05010400u);
    const uint32_t O23 = prm(Ho, Lo, 0x07030602u);
    return make_uint4(prm(O01, E01, 0x05040100u),
                      prm(O01, E01, 0x07060302u),
                      prm(O23, E23, 0x05040100u),
                      prm(O23, E23, 0x07060302u));
}

// async 16B global -> LDS DMA (wave-uniform-base + lane-linear dest)
__device__ __forceinline__ void gld16(void* lds, const void* g) {
    __builtin_amdgcn_global_load_lds(
        (__attribute__((address_space(1))) void*)g,
        (__attribute__((address_space(3))) void*)lds, 16, 0, 0);
}

// ---------------- routing ----------------
__global__ void route_count(const int* __restrict__ topk_idx, int* __restrict__ counts) {
    int p = blockIdx.x * blockDim.x + threadIdx.x;
    if (p < T_ * K_) atomicAdd(&counts[topk_idx[p]], 1);
}

__global__ void route_scan(const int* __restrict__ counts, int* __restrict__ offsets,
                           int* __restrict__ tmap) {
    if (threadIdx.x == 0) {
        int acc = 0, ti = 0;
        for (int e = 0; e < E_; e++) {
            offsets[e] = acc;
            int nt = (counts[e] + 127) >> 7;
            for (int j = 0; j < nt; j++) tmap[ti++] = (e << 16) | j;
            acc += counts[e];
        }
        offsets[E_] = acc;
        for (; ti < 64; ti++) tmap[ti] = -1;
    }
}

__global__ void route_fill(const int* __restrict__ topk_idx, const float* __restrict__ topk_w,
                           int* __restrict__ cursors, const int* __restrict__ offsets,
                           int* __restrict__ tok, float* __restrict__ wgt,
                           int* __restrict__ inv) {
    int p = blockIdx.x * blockDim.x + threadIdx.x;
    if (p < T_ * K_) {
        int e = topk_idx[p];
        int slot = atomicAdd(&cursors[e], 1);
        int idx = offsets[e] + slot;
        tok[idx] = p / K_;
        wgt[idx] = topk_w[p];
        inv[p] = idx;
    }
}

// x f32 -> bf16
__global__ __launch_bounds__(256)
void xcast_kernel(const float* __restrict__ x, uint4* __restrict__ xb) {
    const int i = blockIdx.x * 256 + threadIdx.x;
    const float4 a = ((const float4*)x)[i * 2];
    const float4 b = ((const float4*)x)[i * 2 + 1];
    union { uint4 u; bf16 h[8]; } r;
    r.h[0] = (bf16)a.x; r.h[1] = (bf16)a.y; r.h[2] = (bf16)a.z; r.h[3] = (bf16)a.w;
    r.h[4] = (bf16)b.x; r.h[5] = (bf16)b.y; r.h[6] = (bf16)b.z; r.h[7] = (bf16)b.w;
    xb[i] = r.u;
}

// ---------------- GEMM1 (pipelined, fused LUT dequant) ----------------
// tile: 128 tokens x 64 i for BOTH gate & up. BK=32, double-buffered LDS,
// ONE barrier per k-step; weight loads/x-DMA for step k+1 issued before
// MFMAs of step k.
__global__ __launch_bounds__(256)
void gemm1p_kernel(const bf16* __restrict__ xb,
                   const uint32_t* __restrict__ gate_packed,
                   const float* __restrict__ gate_scales,
                   const uint32_t* __restrict__ up_packed,
                   const float* __restrict__ up_scales,
                   const int* __restrict__ offsets,
                   const int* __restrict__ tmap,
                   const int* __restrict__ tok, bf16* __restrict__ h_buf)
{
    const int tm = tmap[blockIdx.y];
    if (tm < 0) return;
    const int e = tm >> 16, ty = tm & 0xffff;
    const int row0 = offsets[e];
    const int cnt = offsets[e + 1] - row0;
    const int itile = blockIdx.x;

    __shared__ __align__(16) bf16 xs[2][128][32];
    __shared__ __align__(16) bf16 wgs[2][64][32];
    __shared__ __align__(16) bf16 wus[2][64][32];
    __shared__ int toks[128];

    const int tid = threadIdx.x;
    if (tid < 128) {
        int r = ty * 128 + tid;
        toks[tid] = tok[row0 + ((r < cnt) ? r : (cnt - 1))];
    }
    __syncthreads();

    const int srow = tid >> 2;
    const int scol = (tid & 3) * 8;
    const int wcol = tid & 3;
    const size_t t0 = toks[srow], t1 = toks[64 + srow];
    const bf16* xg0 = xb + t0 * H_ + scol;
    const bf16* xg1 = xb + t1 * H_ + scol;
    bf16* lx0[2] = { &xs[0][srow][scol], &xs[1][srow][scol] };
    bf16* lx1[2] = { &xs[0][64 + srow][scol], &xs[1][64 + srow][scol] };

    const int irow = itile * 64 + srow;
    const uint32_t* gp_row = gate_packed + (size_t)e * I_ * (H_ / 8) + (size_t)irow * (H_ / 8) + wcol;
    const uint32_t* up_row = up_packed + (size_t)e * I_ * (H_ / 8) + (size_t)irow * (H_ / 8) + wcol;
    const float* gs_row = gate_scales + (size_t)e * (H_ / G_) * I_ + irow;
    const float* us_row = up_scales + (size_t)e * (H_ / G_) * I_ + irow;
    uint4* lwg[2] = { (uint4*)&wgs[0][srow][wcol * 8], (uint4*)&wgs[1][srow][wcol * 8] };
    uint4* lwu[2] = { (uint4*)&wus[0][srow][wcol * 8], (uint4*)&wus[1][srow][wcol * 8] };

    const int wave = tid >> 6, lane = tid & 63;
    const int wy = wave >> 1, wx = wave & 1;
    const int lrow = lane & 15, kq = lane >> 4;

    f32x4 accg[4][2] = {};
    f32x4 accu[4][2] = {};

    // prologue: stage step 0 into buffer 0
    float sg_c = gs_row[0], su_c = us_row[0];
    uint32_t pg0 = gp_row[0], pu0 = up_row[0];
    gld16(lx0[0], xg0);
    gld16(lx1[0], xg1);
    DequantTab tg = build_tab(sg_c), tu = build_tab(su_c);
    *lwg[0] = dequant8t(pg0, tg);
    *lwu[0] = dequant8t(pu0, tu);
    __syncthreads();

    for (int kg = 0; kg < H_ / G_; kg++) {    // 16 groups x 4 steps
        float sg_n = 0.f, su_n = 0.f;
        if (kg < H_ / G_ - 1) { sg_n = gs_row[(kg + 1) * I_]; su_n = us_row[(kg + 1) * I_]; }
#pragma unroll
        for (int kk = 0; kk < 4; kk++) {
            const int k = kg * 4 + kk;
            const int b = k & 1, nb = b ^ 1;
            const bool hasn = (k < H_ / 32 - 1);
            uint32_t pgn = 0, pun = 0;
            if (hasn) {
                pgn = gp_row[(k + 1) * 4];
                pun = up_row[(k + 1) * 4];
                gld16(lx0[nb], xg0 + (k + 1) * 32);
                gld16(lx1[nb], xg1 + (k + 1) * 32);
            }
            bf16x8 a[4], bg[2], bu[2];
#pragma unroll
            for (int mi = 0; mi < 4; mi++)
                a[mi] = *(const bf16x8*)&xs[b][wy * 64 + mi * 16 + lrow][kq * 8];
#pragma unroll
            for (int ni = 0; ni < 2; ni++) {
                bg[ni] = *(const bf16x8*)&wgs[b][wx * 32 + ni * 16 + lrow][kq * 8];
                bu[ni] = *(const bf16x8*)&wus[b][wx * 32 + ni * 16 + lrow][kq * 8];
            }
#pragma unroll
            for (int mi = 0; mi < 4; mi++)
#pragma unroll
                for (int ni = 0; ni < 2; ni++) {
                    accg[mi][ni] = __builtin_amdgcn_mfma_f32_16x16x32_bf16(a[mi], bg[ni], accg[mi][ni], 0, 0, 0);
                    accu[mi][ni] = __builtin_amdgcn_mfma_f32_16x16x32_bf16(a[mi], bu[ni], accu[mi][ni], 0, 0, 0);
                }
            if (hasn) {
                if (kk == 3) { tg = build_tab(sg_n); tu = build_tab(su_n); }
                *lwg[nb] = dequant8t(pgn, tg);
                *lwu[nb] = dequant8t(pun, tu);
            }
            __syncthreads();
        }
    }

    // epilogue: h = silu(g)*u -> bf16. C layout: col=lane&15, row=(lane>>4)*4+r
#pragma unroll
    for (int mi = 0; mi < 4; mi++)
#pragma unroll
        for (int ni = 0; ni < 2; ni++) {
            const int icol = itile * 64 + wx * 32 + ni * 16 + lrow;
#pragma unroll
            for (int r = 0; r < 4; r++) {
                const int grow = ty * 128 + wy * 64 + mi * 16 + kq * 4 + r;
                if (grow < cnt) {
                    const float gv = accg[mi][ni][r];
                    const float hv = gv / (1.f + __expf(-gv)) * accu[mi][ni][r];
                    h_buf[(size_t)(row0 + grow) * I_ + icol] = (bf16)hv;
                }
            }
        }
}

// ---------------- GEMM2 (pipelined): y_pair[pair] = wgt * (h @ Wd^T) ----------------
// tile: 128 tokens x 128 h-cols, BK=32, double-buffered, one barrier/step,
// plain stores to y_pair (no atomics).
__global__ __launch_bounds__(256)
void gemm2p_kernel(const bf16* __restrict__ h_buf,
                   const uint32_t* __restrict__ down_packed,
                   const float* __restrict__ down_scales,
                   const int* __restrict__ offsets,
                   const int* __restrict__ tmap,
                   const int* __restrict__ tok,
                   const float* __restrict__ wgt, float* __restrict__ yp)
{
    const int tm = tmap[blockIdx.y];
    if (tm < 0) return;
    const int e = tm >> 16, ty = tm & 0xffff;
    const int row0 = offsets[e];
    const int cnt = offsets[e + 1] - row0;
    const int htile = blockIdx.x;

    __shared__ __align__(16) bf16 hs[2][128][32];
    __shared__ __align__(16) bf16 wds[2][128][32];
    __shared__ float wgts[128];

    const int tid = threadIdx.x;
    if (tid < 128) {
        int r = ty * 128 + tid;
        wgts[tid] = (r < cnt) ? wgt[row0 + r] : 0.f;
    }
    __syncthreads();

    const int srow = tid >> 2;
    const int scol = (tid & 3) * 8;
    const int m0 = ty * 128 + srow;
    const int hr0 = row0 + ((m0 < cnt) ? m0 : (cnt - 1));
    const int m1 = m0 + 64;
    const int hr1 = row0 + ((m1 < cnt) ? m1 : (cnt - 1));
    const bf16* hg0 = h_buf + (size_t)hr0 * I_ + scol;
    const bf16* hg1 = h_buf + (size_t)hr1 * I_ + scol;
    bf16* lh0[2] = { &hs[0][srow][scol], &hs[1][srow][scol] };
    bf16* lh1[2] = { &hs[0][64 + srow][scol], &hs[1][64 + srow][scol] };

    // weight staging: 1 of 128 rows, 2 consecutive u32 (16 fp4) per step
    const int srow2 = tid >> 1;
    const int wcol2 = (tid & 1) * 2;
    const int hrow = htile * 128 + srow2;
    const uint32_t* dp_row = down_packed + (size_t)e * H_ * (I_ / 8) + (size_t)hrow * (I_ / 8) + wcol2;
    const float* ds_row = down_scales + (size_t)e * (I_ / G_) * H_ + hrow;
    uint4* lwd0[2] = { (uint4*)&wds[0][srow2][wcol2 * 8], (uint4*)&wds[1][srow2][wcol2 * 8] };
    uint4* lwd1[2] = { (uint4*)&wds[0][srow2][wcol2 * 8 + 8], (uint4*)&wds[1][srow2][wcol2 * 8 + 8] };

    const int wave = tid >> 6, lane = tid & 63;
    const int wy = wave >> 1, wx = wave & 1;
    const int lrow = lane & 15, kq = lane >> 4;

    f32x4 acc[4][4] = {};

    // prologue: stage step 0 into buffer 0
    float sd_c = ds_row[0];
    uint32_t pd0 = dp_row[0], pd1 = dp_row[1];
    gld16(lh0[0], hg0);
    gld16(lh1[0], hg1);
    DequantTab td = build_tab(sd_c);
    *lwd0[0] = dequant8t(pd0, td);
    *lwd1[0] = dequant8t(pd1, td);
    __syncthreads();

    for (int kg = 0; kg < I_ / G_; kg++) {    // 11 groups x 4 steps
        float sd_n = 0.f;
        if (kg < I_ / G_ - 1) sd_n = ds_row[(kg + 1) * H_];
#pragma unroll
        for (int kk = 0; kk < 4; kk++) {
            const int k = kg * 4 + kk;
            const int b = k & 1, nb = b ^ 1;
            const bool hasn = (k < I_ / 32 - 1);
            uint32_t pdn0 = 0, pdn1 = 0;
            if (hasn) {
                pdn0 = dp_row[(k + 1) * 4];
                pdn1 = dp_row[(k + 1) * 4 + 1];
                gld16(lh0[nb], hg0 + (k + 1) * 32);
                gld16(lh1[nb], hg1 + (k + 1) * 32);
            }
            bf16x8 a[4], bb[4];
#pragma unroll
            for (int mi = 0; mi < 4; mi++)
                a[mi] = *(const bf16x8*)&hs[b][wy * 64 + mi * 16 + lrow][kq * 8];
#pragma unroll
            for (int ni = 0; ni < 4; ni++)
                bb[ni] = *(const bf16x8*)&wds[b][wx * 64 + ni * 16 + lrow][kq * 8];
#pragma unroll
            for (int mi = 0; mi < 4; mi++)
#pragma unroll
                for (int ni = 0; ni < 4; ni++)
                    acc[mi][ni] = __builtin_amdgcn_mfma_f32_16x16x32_bf16(a[mi], bb[ni], acc[mi][ni], 0, 0, 0);
            if (hasn) {
                if (kk == 3) td = build_tab(sd_n);
                *lwd0[nb] = dequant8t(pdn0, td);
                *lwd1[nb] = dequant8t(pdn1, td);
            }
            __syncthreads();
        }
    }

    // epilogue: plain stores of wgt-scaled partials
#pragma unroll
    for (int mi = 0; mi < 4; mi++)
#pragma unroll
        for (int ni = 0; ni < 4; ni++) {
            const int col = htile * 128 + wx * 64 + ni * 16 + lrow;
#pragma unroll
            for (int r = 0; r < 4; r++) {
                const int lr = wy * 64 + mi * 16 + kq * 4 + r;
                if (ty * 128 + lr < cnt)
                    yp[(size_t)(row0 + ty * 128 + lr) * H_ + col] = acc[mi][ni][r] * wgts[lr];
            }
        }
}

// ---------------- combine: out[t] = sum over K pairs ----------------
__global__ __launch_bounds__(256)
void combine_kernel(const float* __restrict__ yp, const int* __restrict__ inv,
                    float* __restrict__ out) {
    const int idx = blockIdx.x * 256 + threadIdx.x;   // T_*H_/4 units
    const int t = idx >> 9;                            // / (H_/4 = 512)
    const int c = idx & 511;
    const float4 a = ((const float4*)yp)[(size_t)inv[t * 2] * (H_ / 4) + c];
    const float4 b = ((const float4*)yp)[(size_t)inv[t * 2 + 1] * (H_ / 4) + c];
    float4 o;
    o.x = a.x + b.x; o.y = a.y + b.y; o.z = a.z + b.z; o.w = a.w + b.w;
    ((float4*)out)[idx] = o;
}

extern "C" void kernel_launch(void* const* d_in, const int* in_sizes, int n_in,
                              void* d_out, int out_size, void* d_ws, size_t ws_size,
                              hipStream_t stream) {
    const float* x = (const float*)d_in[0];
    const uint32_t* gate_packed = (const uint32_t*)d_in[1];
    const float* gate_scales = (const float*)d_in[2];
    const uint32_t* up_packed = (const uint32_t*)d_in[3];
    const float* up_scales = (const float*)d_in[4];
    const uint32_t* down_packed = (const uint32_t*)d_in[5];
    const float* down_scales = (const float*)d_in[6];
    const int* topk_idx = (const int*)d_in[7];
    const float* topk_w = (const float*)d_in[8];
    float* out = (float*)d_out;

    // workspace layout (bytes)
    char* ws = (char*)d_ws;
    int* counts  = (int*)ws;              // 32
    int* cursors = (int*)(ws + 32);       // 32
    int* offsets = (int*)(ws + 64);       // 64
    int* tmap    = (int*)(ws + 128);      // 256 (64 ints)
    int* tok     = (int*)(ws + 512);      // 16384
    float* wgt   = (float*)(ws + 16896);  // 16384
    int* inv     = (int*)(ws + 33280);    // 16384
    bf16* h_buf  = (bf16*)(ws + 49664);   // 11,534,336
    bf16* xb     = (bf16*)(ws + 49664 + 11534336ull);      // 8,388,608
    float* yp    = (float*)(ws + 49664 + 11534336ull + 8388608ull); // 33,554,432

    hipMemsetAsync(d_ws, 0, 512, stream);

    route_count<<<(T_ * K_ + 255) / 256, 256, 0, stream>>>(topk_idx, counts);
    route_scan<<<1, 64, 0, stream>>>(counts, offsets, tmap);
    route_fill<<<(T_ * K_ + 255) / 256, 256, 0, stream>>>(topk_idx, topk_w, cursors, offsets,
                                                          tok, wgt, inv);
    xcast_kernel<<<T_ * H_ / 8 / 256, 256, 0, stream>>>(x, (uint4*)xb);

    dim3 g1(I_ / 64, 40);
    gemm1p_kernel<<<g1, 256, 0, stream>>>(xb, gate_packed, gate_scales, up_packed, up_scales,
                                          offsets, tmap, tok, h_buf);
    dim3 g2(H_ / 128, 40);
    gemm2p_kernel<<<g2, 256, 0, stream>>>(h_buf, down_packed, down_scales,
                                          offsets, tmap, tok, wgt, yp);
    combine_kernel<<<T_ * H_ / 4 / 256, 256, 0, stream>>>(yp, inv, out);
}